// Round 1
// baseline (716.712 us; speedup 1.0000x reference)
//
#include <hip/hip_runtime.h>

#define N   160
#define SX  (N * N)
#define SY  N

// Round-7: z-vectorization. Each thread computes 4 consecutive z voxels via
// float4 loads (one load instruction = 1 KB/wave instead of 256 B), cutting
// VMEM instruction count ~3.7x (46 -> 12.5 loads/voxel) and address VALU ~4x
// while keeping HBM bytes identical. z+-1 neighbors come from adjacent vector
// elements; only 2 edge scalars per row (L1 hits). x/y boundary handling keeps
// the proven clamped-offset form. XCD locality: 1-D grid remapped in-kernel so
// each XCD owns 5 (b,ytile) groups swept x-contiguously -> x+-1 planes hit the
// local L2 (strictly cleaner than the old mod-40 trick).

struct R4 { float a[4]; };
struct R6 { float a[6]; };

__device__ __forceinline__ R4 ld4(const float* __restrict__ p, int row, int z0) {
    const float4 m = *reinterpret_cast<const float4*>(p + row * N + z0);
    R4 r; r.a[0] = m.x; r.a[1] = m.y; r.a[2] = m.z; r.a[3] = m.w;
    return r;
}

__device__ __forceinline__ R6 ld6(const float* __restrict__ p, int row, int z0,
                                  int zL, int zR) {
    const float4 m = *reinterpret_cast<const float4*>(p + row * N + z0);
    R6 r;
    r.a[0] = p[row * N + z0 + zL];
    r.a[1] = m.x; r.a[2] = m.y; r.a[3] = m.z; r.a[4] = m.w;
    r.a[5] = p[row * N + z0 + zR];
    return r;
}

__global__ __launch_bounds__(320, 4) void piano_energy_kernel(
    const float* __restrict__ C,   const float* __restrict__ Vx,
    const float* __restrict__ Vy,  const float* __restrict__ Vz,
    const float* __restrict__ Dxx, const float* __restrict__ Dxy,
    const float* __restrict__ Dxz, const float* __restrict__ Dyy,
    const float* __restrict__ Dyz, const float* __restrict__ Dzz,
    float* __restrict__ out)
{
    const int tz = threadIdx.x;            // 0..39, 4 z-voxels per thread
    const int z0 = tz << 2;

    // XCD-contiguous x-sweep (HW: XCD = blockIdx % 8). Each XCD gets 800
    // consecutive work ids = 5 full (b,ytile) groups, each swept x=0..159.
    const int id = blockIdx.x;             // 0..6399
    const int w  = (id & 7) * 800 + (id >> 3);
    const int x  = w % N;
    const int g  = w / N;                  // 0..39 = b*20 + ytile
    const int y  = (g % 20) * 8 + threadIdx.y;
    const int b  = g / 20;

    const int r0  = (b * N + x) * N + y;   // row index (rows of 160 floats)
    const int idx = r0 * N + z0;

    const bool xlo = (x > 0), xhi = (x < N - 1);
    const bool ylo = (y > 0), yhi = (y < N - 1);
    const bool zlo0 = (tz > 0), zhi3 = (tz < 39);   // z flags for elems 0 / 3

    const int oxp_r = xhi ?  N : 0, oxm_r = xlo ? -N : 0;   // row-unit offsets
    const int oyp_r = yhi ?  1 : 0, oym_r = ylo ? -1 : 0;
    const int zL = zlo0 ? -1 : 0;          // in-row edge-scalar offsets
    const int zR = zhi3 ?  4 : 3;

    const float sx = (xlo && xhi) ? 0.5f : 1.f;
    const float sy = (ylo && yhi) ? 0.5f : 1.f;

    // element-unit offsets for the (rare) boundary cross-term path
    const int oxp = xhi ? SX : 0, ofx0 = xhi ? 0 : -SX;
    const int oyp = yhi ? SY : 0, ofy0 = yhi ? 0 : -SY;
    const int obx1 = xlo ? 0 : SX, obx0 = obx1 - SX;
    const int oby1 = ylo ? 0 : SY, oby0 = oby1 - SY;

    // ---- C neighborhood: 5 rows (f4 + 2 edge scalars) + 2 corner rows ----
    const R6 Cc  = ld6(C, r0,         z0, zL, zR);
    const R6 Cxp = ld6(C, r0 + oxp_r, z0, zL, zR);
    const R6 Cxm = ld6(C, r0 + oxm_r, z0, zL, zR);
    const R6 Cyp = ld6(C, r0 + oyp_r, z0, zL, zR);
    const R6 Cym = ld6(C, r0 + oym_r, z0, zL, zR);
    const R4 Ca  = ld4(C, r0 + oxm_r + oyp_r, z0);   // (x-1, y+1)
    const R4 Cb  = ld4(C, r0 + oxp_r + oym_r, z0);   // (x+1, y-1)

    R4 Cx2 = {}; R4 Cy2 = {};
    if (!xlo && xhi) Cx2 = ld4(C, r0 + 2 * N, z0);   // x == 0 plane only
    if (!ylo && yhi) Cy2 = ld4(C, r0 + 2, z0);       // y == 0 rows only

    float Cxc[4], Cyc[4], Czc[4];
    float sXXa[4], sYYa[4], sZZa[4], cXYa[4], cXZa[4], cYZa[4];

#pragma unroll
    for (int e = 0; e < 4; ++e) {
        const bool zlo = (e > 0) || zlo0;
        const bool zhi = (e < 3) || zhi3;
        const float sz = (zlo && zhi) ? 0.5f : 1.f;
        const float c0  = Cc.a[e + 1];
        const float cxp = Cxp.a[e + 1], cxm = Cxm.a[e + 1];
        const float cyp = Cyp.a[e + 1], cym = Cym.a[e + 1];
        const float czp = zhi ? Cc.a[e + 2] : c0;
        const float czm = zlo ? Cc.a[e]     : c0;

        Cxc[e] = sx * (cxp - cxm);
        Cyc[e] = sy * (cyp - cym);
        Czc[e] = sz * (czp - czm);

        float sXX, sYY, sZZ;
        if (!xhi)      sXX = 0.f;
        else if (xlo)  sXX = cxp - 2.f * c0 + cxm;
        else           sXX = Cx2.a[e] - 2.f * cxp + c0;
        if (!yhi)      sYY = 0.f;
        else if (ylo)  sYY = cyp - 2.f * c0 + cym;
        else           sYY = Cy2.a[e] - 2.f * cyp + c0;
        if (!zhi)      sZZ = 0.f;
        else if (zlo)  sZZ = czp - 2.f * c0 + czm;
        else           sZZ = Cc.a[(e + 3 > 5) ? 5 : e + 3] - 2.f * czp + c0;
        sXXa[e] = sXX; sYYa[e] = sYY; sZZa[e] = sZZ;

        const int gi = idx + e;
        if (xlo && xhi && ylo && yhi) {       // x part block-uniform
            cXYa[e] = cxp + cxm + cyp + cym - 2.f * c0 - Ca.a[e] - Cb.a[e];
        } else {
            cXYa[e] = (C[gi + obx1 + oyp] - C[gi + obx1 + ofy0])
                    - (C[gi + obx0 + oyp] - C[gi + obx0 + ofy0])
                    + (C[gi + oby1 + oxp] - C[gi + oby1 + ofx0])
                    - (C[gi + oby0 + oxp] - C[gi + oby0 + ofx0]);
        }
        if (xlo && xhi && zlo && zhi) {
            cXZa[e] = cxp + cxm + czp + czm - 2.f * c0
                    - Cxp.a[e] - Cxm.a[e + 2];      // (x+1,z-1),(x-1,z+1)
        } else {
            const int ozp = zhi ? 1 : 0;
            const int obz1 = zlo ? 0 : 1, obz0 = obz1 - 1;
            const int ofz0 = zhi ? 0 : -1;
            cXZa[e] = (C[gi + obz1 + oxp] - C[gi + obz1 + ofx0])
                    - (C[gi + obz0 + oxp] - C[gi + obz0 + ofx0])
                    + (C[gi + obx1 + ozp] - C[gi + obx1 + ofz0])
                    - (C[gi + obx0 + ozp] - C[gi + obx0 + ofz0]);
        }
        if (ylo && yhi && zlo && zhi) {
            cYZa[e] = cyp + cym + czp + czm - 2.f * c0
                    - Cyp.a[e] - Cym.a[e + 2];      // (y+1,z-1),(y-1,z+1)
        } else {
            const int ozp = zhi ? 1 : 0;
            const int obz1 = zlo ? 0 : 1, obz0 = obz1 - 1;
            const int ofz0 = zhi ? 0 : -1;
            cYZa[e] = (C[gi + obz1 + oyp] - C[gi + obz1 + ofy0])
                    - (C[gi + obz0 + oyp] - C[gi + obz0 + ofy0])
                    + (C[gi + oby1 + ozp] - C[gi + oby1 + ofz0])
                    - (C[gi + oby0 + ozp] - C[gi + oby0 + ofz0]);
        }
    }

    float t1a[4], t2a[4], t3a[4], acc[4];

    {   // Dxx: t1 = dDxx_x ; acc = Dxx0 * sXX
        const R4 c = ld4(Dxx, r0, z0);
        const R4 p = ld4(Dxx, r0 + oxp_r, z0);
        const R4 m = ld4(Dxx, r0 + oxm_r, z0);
#pragma unroll
        for (int e = 0; e < 4; ++e) {
            t1a[e] = sx * (p.a[e] - m.a[e]);
            acc[e] = c.a[e] * sXXa[e];
        }
    }
    {   // Dxy: t1 += dDxy_y, t2 = dDxy_x ; acc += Dxy0 * cXY
        const R4 c  = ld4(Dxy, r0, z0);
        const R4 xp = ld4(Dxy, r0 + oxp_r, z0);
        const R4 xm = ld4(Dxy, r0 + oxm_r, z0);
        const R4 yp = ld4(Dxy, r0 + oyp_r, z0);
        const R4 ym = ld4(Dxy, r0 + oym_r, z0);
#pragma unroll
        for (int e = 0; e < 4; ++e) {
            t1a[e] += sy * (yp.a[e] - ym.a[e]);
            t2a[e]  = sx * (xp.a[e] - xm.a[e]);
            acc[e] += c.a[e] * cXYa[e];
        }
    }
    {   // Dxz: t1 += dDxz_z, t3 = dDxz_x ; acc += Dxz0 * cXZ
        const R6 c  = ld6(Dxz, r0, z0, zL, zR);
        const R4 xp = ld4(Dxz, r0 + oxp_r, z0);
        const R4 xm = ld4(Dxz, r0 + oxm_r, z0);
#pragma unroll
        for (int e = 0; e < 4; ++e) {
            const bool zlo = (e > 0) || zlo0;
            const bool zhi = (e < 3) || zhi3;
            const float sz = (zlo && zhi) ? 0.5f : 1.f;
            const float zpv = zhi ? c.a[e + 2] : c.a[e + 1];
            const float zmv = zlo ? c.a[e]     : c.a[e + 1];
            t1a[e] += sz * (zpv - zmv);
            t3a[e]  = sx * (xp.a[e] - xm.a[e]);
            acc[e] += c.a[e + 1] * cXZa[e];
        }
    }
    {   // Dyy: t2 += dDyy_y ; acc += Dyy0 * sYY
        const R4 c  = ld4(Dyy, r0, z0);
        const R4 yp = ld4(Dyy, r0 + oyp_r, z0);
        const R4 ym = ld4(Dyy, r0 + oym_r, z0);
#pragma unroll
        for (int e = 0; e < 4; ++e) {
            t2a[e] += sy * (yp.a[e] - ym.a[e]);
            acc[e] += c.a[e] * sYYa[e];
        }
    }
    {   // Dyz: t2 += dDyz_z, t3 += dDyz_y ; acc += Dyz0 * cYZ
        const R6 c  = ld6(Dyz, r0, z0, zL, zR);
        const R4 yp = ld4(Dyz, r0 + oyp_r, z0);
        const R4 ym = ld4(Dyz, r0 + oym_r, z0);
#pragma unroll
        for (int e = 0; e < 4; ++e) {
            const bool zlo = (e > 0) || zlo0;
            const bool zhi = (e < 3) || zhi3;
            const float sz = (zlo && zhi) ? 0.5f : 1.f;
            const float zpv = zhi ? c.a[e + 2] : c.a[e + 1];
            const float zmv = zlo ? c.a[e]     : c.a[e + 1];
            t2a[e] += sz * (zpv - zmv);
            t3a[e] += sy * (yp.a[e] - ym.a[e]);
            acc[e] += c.a[e + 1] * cYZa[e];
        }
    }
    {   // Dzz: t3 += dDzz_z ; acc += Dzz0 * sZZ
        const R6 c = ld6(Dzz, r0, z0, zL, zR);
#pragma unroll
        for (int e = 0; e < 4; ++e) {
            const bool zlo = (e > 0) || zlo0;
            const bool zhi = (e < 3) || zhi3;
            const float sz = (zlo && zhi) ? 0.5f : 1.f;
            const float zpv = zhi ? c.a[e + 2] : c.a[e + 1];
            const float zmv = zlo ? c.a[e]     : c.a[e + 1];
            t3a[e] += sz * (zpv - zmv);
            acc[e] += c.a[e + 1] * sZZa[e];
        }
    }

#pragma unroll
    for (int e = 0; e < 4; ++e)
        acc[e] += t1a[e] * Cxc[e] + t2a[e] * Cyc[e] + t3a[e] * Czc[e];

    // ---- advection (upwind); C grads recomputed from live C rows ----
    {   // Vx
        const R4 c = ld4(Vx, r0, z0);
        const R4 p = ld4(Vx, r0 + oxp_r, z0);
        const R4 m = ld4(Vx, r0 + oxm_r, z0);
#pragma unroll
        for (int e = 0; e < 4; ++e) {
            const float c0  = Cc.a[e + 1];
            const float cxp = Cxp.a[e + 1], cxm = Cxm.a[e + 1];
            const float Cx_f = xhi ? (cxp - c0) : (c0 - cxm);
            const float Cx_b = xlo ? (c0 - cxm) : (cxp - c0);
            const float v = c.a[e];
            acc[e] -= v * ((v > 0.f) ? Cx_b : Cx_f)
                    + c0 * (sx * (p.a[e] - m.a[e]));
        }
    }
    {   // Vy
        const R4 c = ld4(Vy, r0, z0);
        const R4 p = ld4(Vy, r0 + oyp_r, z0);
        const R4 m = ld4(Vy, r0 + oym_r, z0);
#pragma unroll
        for (int e = 0; e < 4; ++e) {
            const float c0  = Cc.a[e + 1];
            const float cyp = Cyp.a[e + 1], cym = Cym.a[e + 1];
            const float Cy_f = yhi ? (cyp - c0) : (c0 - cym);
            const float Cy_b = ylo ? (c0 - cym) : (cyp - c0);
            const float v = c.a[e];
            acc[e] -= v * ((v > 0.f) ? Cy_b : Cy_f)
                    + c0 * (sy * (p.a[e] - m.a[e]));
        }
    }
    {   // Vz
        const R6 c = ld6(Vz, r0, z0, zL, zR);
#pragma unroll
        for (int e = 0; e < 4; ++e) {
            const bool zlo = (e > 0) || zlo0;
            const bool zhi = (e < 3) || zhi3;
            const float sz = (zlo && zhi) ? 0.5f : 1.f;
            const float c0  = Cc.a[e + 1];
            const float czp = zhi ? Cc.a[e + 2] : c0;
            const float czm = zlo ? Cc.a[e]     : c0;
            const float Cz_f = zhi ? (czp - c0) : (c0 - czm);
            const float Cz_b = zlo ? (c0 - czm) : (czp - c0);
            const float v = c.a[e + 1];
            const float dVz = sz * ((zhi ? c.a[e + 2] : c.a[e + 1])
                                  - (zlo ? c.a[e]     : c.a[e + 1]));
            acc[e] -= v * ((v > 0.f) ? Cz_b : Cz_f) + c0 * dVz;
        }
    }

    float4 o;
    o.x = acc[0]; o.y = acc[1]; o.z = acc[2]; o.w = acc[3];
    *reinterpret_cast<float4*>(out + idx) = o;
}

extern "C" void kernel_launch(void* const* d_in, const int* in_sizes, int n_in,
                              void* d_out, int out_size, void* d_ws, size_t ws_size,
                              hipStream_t stream) {
    const float* C   = (const float*)d_in[0];
    const float* Vx  = (const float*)d_in[1];
    const float* Vy  = (const float*)d_in[2];
    const float* Vz  = (const float*)d_in[3];
    const float* Dxx = (const float*)d_in[4];
    const float* Dxy = (const float*)d_in[5];
    const float* Dxz = (const float*)d_in[6];
    const float* Dyy = (const float*)d_in[7];
    const float* Dyz = (const float*)d_in[8];
    const float* Dzz = (const float*)d_in[9];
    float* out = (float*)d_out;

    // 6400 blocks = 2 batches * 20 y-tiles * 160 x-planes; 320 thr = 5 waves.
    dim3 grid(6400, 1, 1);
    dim3 block(40, 8, 1);
    hipLaunchKernelGGL(piano_energy_kernel, grid, block, 0, stream,
                       C, Vx, Vy, Vz, Dxx, Dxy, Dxz, Dyy, Dyz, Dzz, out);
}

// Round 2
// 519.061 us; speedup vs baseline: 1.3808x; 1.3808x over previous
//
#include <hip/hip_runtime.h>

#define N    160
#define SX   (N * N)
#define SY   N
#define ROW  160

// Round-8: LDS-staged stencil. Round-7's register-blocked float4 variant
// spilled to scratch (WRITE_SIZE 491 MB vs 32 MB ideal -> 533 us), confirming
// the round-1 finding that per-thread register neighborhoods lose here.
// This version keeps the proven 1-voxel/thread round-6 compute (VGPR~32-64,
// all scalar locals) but moves ALL neighborhood state to LDS:
//   block = one x plane x 4-y tile x full z (640 thr). Cooperative float4
//   staging of 10 arrays (98 rows = 62.7 KB LDS, 2 blocks/CU) gives ~6
//   independent wide loads/thread instead of 46 dependent scalars -> MLP
//   hides HBM/L2 latency. Compute reads are ds_read_b32 at consecutive z
//   (2-way bank alias = free on CDNA4).
// LDS row map: C:0 Dxx:18 Dxy:30 Dxz:48 Vx:60 Dyy:72 Dyz:78 Vy:84 Dzz:90 Vz:94

template<int P, int R, bool HALO>
__device__ __forceinline__ void stage(float* __restrict__ lds, int dstRow,
                                      const float* __restrict__ src,
                                      int b, int x, int y0, int tid)
{
    const int tot = P * R * 40;            // 40 float4 chunks per row
    for (int u = tid; u < tot; u += 640) {
        const int c = u % 40;
        const int r = (u / 40) % R;
        const int p = u / (40 * R);
        const int px = (P == 3) ? min(max(x + p - 1, 0), N - 1) : x;
        int gy = HALO ? (y0 + r - 1) : (y0 + r);
        if (HALO) gy = min(max(gy, 0), N - 1);
        const float4 v = *reinterpret_cast<const float4*>(
            src + ((b * N + px) * N + gy) * N + (c << 2));
        *reinterpret_cast<float4*>(lds + (dstRow + p * R + r) * ROW + (c << 2)) = v;
    }
}

__global__ __launch_bounds__(640, 2) void piano_energy_kernel(
    const float* __restrict__ C,   const float* __restrict__ Vx,
    const float* __restrict__ Vy,  const float* __restrict__ Vz,
    const float* __restrict__ Dxx, const float* __restrict__ Dxy,
    const float* __restrict__ Dxz, const float* __restrict__ Dyy,
    const float* __restrict__ Dyz, const float* __restrict__ Dzz,
    float* __restrict__ out)
{
    __shared__ float lds[98 * ROW];        // 62,720 B

    // XCD-contiguous x-sweep: XCD = blockIdx % 8; each XCD owns 1600
    // consecutive work ids = 10 (b,ytile) groups, each swept x = 0..159,
    // so the x+-1 planes staged by the previous block are L2-resident.
    const int id = blockIdx.x;             // 0..12799
    const int w  = (id & 7) * 1600 + (id >> 3);
    const int x  = w % N;
    const int g  = w / N;                  // 0..79 = b*40 + ytile
    const int y0 = (g % 40) * 4;
    const int b  = g / 40;

    const int z   = threadIdx.x;           // 0..159
    const int ty  = threadIdx.y;           // 0..3
    const int tid = ty * 160 + z;
    const int y   = y0 + ty;
    const int jc  = ty + 1;                // center row slot in 6-row arrays

    stage<3, 6, true >(lds,  0, C,   b, x, y0, tid);
    stage<3, 4, false>(lds, 18, Dxx, b, x, y0, tid);
    stage<3, 6, true >(lds, 30, Dxy, b, x, y0, tid);
    stage<3, 4, false>(lds, 48, Dxz, b, x, y0, tid);
    stage<3, 4, false>(lds, 60, Vx,  b, x, y0, tid);
    stage<1, 6, true >(lds, 72, Dyy, b, x, y0, tid);
    stage<1, 6, true >(lds, 78, Dyz, b, x, y0, tid);
    stage<1, 6, true >(lds, 84, Vy,  b, x, y0, tid);
    stage<1, 4, false>(lds, 90, Dzz, b, x, y0, tid);
    stage<1, 4, false>(lds, 94, Vz,  b, x, y0, tid);
    __syncthreads();

    const int idx = ((b * N + x) * N + y) * N + z;

    const bool xlo = (x > 0), xhi = (x < N - 1);
    const bool ylo = (y > 0), yhi = (y < N - 1);
    const bool zlo = (z > 0), zhi = (z < N - 1);

    // clamped neighbor slots (LDS units), mirroring round-6 clamped offsets
    const int xp = 1 + (xhi ? 1 : 0), xm = 1 - (xlo ? 1 : 0);   // plane slot
    const int yp = jc + (yhi ? 1 : 0), ym = jc - (ylo ? 1 : 0); // row slot
    const int zp = z + (zhi ? 1 : 0),  zm = z - (zlo ? 1 : 0);  // z index

    const float sx = (xlo && xhi) ? 0.5f : 1.f;
    const float sy = (ylo && yhi) ? 0.5f : 1.f;
    const float sz = (zlo && zhi) ? 0.5f : 1.f;

#define CL(p,j,zz)   lds[((p) * 6 + (j)) * ROW + (zz)]
#define DXXL(p,zz)   lds[(18 + (p) * 4 + ty) * ROW + (zz)]
#define DXYL(p,j,zz) lds[(30 + (p) * 6 + (j)) * ROW + (zz)]
#define DXZL(p,zz)   lds[(48 + (p) * 4 + ty) * ROW + (zz)]
#define VXL(p,zz)    lds[(60 + (p) * 4 + ty) * ROW + (zz)]
#define DYYL(j,zz)   lds[(72 + (j)) * ROW + (zz)]
#define DYZL(j,zz)   lds[(78 + (j)) * ROW + (zz)]
#define VYL(j,zz)    lds[(84 + (j)) * ROW + (zz)]
#define DZZL(zz)     lds[(90 + ty) * ROW + (zz)]
#define VZL(zz)      lds[(94 + ty) * ROW + (zz)]

    // ---- C face neighborhood ----
    const float c0  = CL(1, jc, z);
    const float cxp = CL(xp, jc, z), cxm = CL(xm, jc, z);
    const float cyp = CL(1, yp, z),  cym = CL(1, ym, z);
    const float czp = CL(1, jc, zp), czm = CL(1, jc, zm);

    const float Cx_c = sx * (cxp - cxm);
    const float Cy_c = sy * (cyp - cym);
    const float Cz_c = sz * (czp - czm);
    const float Cx_f = xhi ? (cxp - c0) : (c0 - cxm);
    const float Cy_f = yhi ? (cyp - c0) : (c0 - cym);
    const float Cz_f = zhi ? (czp - c0) : (c0 - czm);
    const float Cx_b = xlo ? (c0 - cxm) : (cxp - c0);
    const float Cy_b = ylo ? (c0 - cym) : (cyp - c0);
    const float Cz_b = zlo ? (c0 - czm) : (czp - c0);

    // pure second derivatives
    float sXX, sYY, sZZ;
    if (!xhi)      sXX = 0.f;
    else if (xlo)  sXX = cxp - 2.f * c0 + cxm;
    else           sXX = C[idx + 2 * SX] - 2.f * cxp + c0;   // x==0 (uniform)
    if (!yhi)      sYY = 0.f;
    else if (ylo)  sYY = cyp - 2.f * c0 + cym;
    else           sYY = CL(1, jc + 2, z) - 2.f * cyp + c0;  // y==0 -> row 3
    if (!zhi)      sZZ = 0.f;
    else if (zlo)  sZZ = czp - 2.f * c0 + czm;
    else           sZZ = CL(1, jc, 2) - 2.f * czp + c0;      // z==0

    // boundary-path clamped offsets (LDS units)
    const int obx1 = xlo ? 0 : 1, obx0 = obx1 - 1;
    const int oby1 = ylo ? 0 : 1, oby0 = oby1 - 1;
    const int obz1 = zlo ? 0 : 1, obz0 = obz1 - 1;
    const int ofx0 = xhi ? 0 : -1;
    const int ofy0 = yhi ? 0 : -1;
    const int ofz0 = zhi ? 0 : -1;

    float cXY;
    if (xlo && xhi && ylo && yhi) {
        cXY = cxp + cxm + cyp + cym - 2.f * c0
            - CL(0, jc + 1, z) - CL(2, jc - 1, z);
    } else {
        cXY = (CL(1 + obx1, yp, z) - CL(1 + obx1, jc + ofy0, z))
            - (CL(1 + obx0, yp, z) - CL(1 + obx0, jc + ofy0, z))
            + (CL(xp, jc + oby1, z) - CL(1 + ofx0, jc + oby1, z))
            - (CL(xp, jc + oby0, z) - CL(1 + ofx0, jc + oby0, z));
    }

    float cXZ;
    if (xlo && xhi && zlo && zhi) {
        cXZ = cxp + cxm + czp + czm - 2.f * c0
            - CL(2, jc, z - 1) - CL(0, jc, z + 1);
    } else {
        cXZ = (CL(xp, jc, z + obz1) - CL(1 + ofx0, jc, z + obz1))
            - (CL(xp, jc, z + obz0) - CL(1 + ofx0, jc, z + obz0))
            + (CL(1 + obx1, jc, zp) - CL(1 + obx1, jc, z + ofz0))
            - (CL(1 + obx0, jc, zp) - CL(1 + obx0, jc, z + ofz0));
    }

    float cYZ;
    if (ylo && yhi && zlo && zhi) {
        cYZ = cyp + cym + czp + czm - 2.f * c0
            - CL(1, jc + 1, z - 1) - CL(1, jc - 1, z + 1);
    } else {
        cYZ = (CL(1, yp, z + obz1) - CL(1, jc + ofy0, z + obz1))
            - (CL(1, yp, z + obz0) - CL(1, jc + ofy0, z + obz0))
            + (CL(1, jc + oby1, zp) - CL(1, jc + oby1, z + ofz0))
            - (CL(1, jc + oby0, zp) - CL(1, jc + oby0, z + ofz0));
    }

    // ---- diffusion-tensor divergence terms ----
    const float dDxx_x = sx * (DXXL(xp, z) - DXXL(xm, z));
    const float dDxy_x = sx * (DXYL(xp, jc, z) - DXYL(xm, jc, z));
    const float dDxy_y = sy * (DXYL(1, yp, z) - DXYL(1, ym, z));
    const float dDxz_x = sx * (DXZL(xp, z) - DXZL(xm, z));
    const float dDxz_z = sz * (DXZL(1, zp) - DXZL(1, zm));
    const float dDyy_y = sy * (DYYL(yp, z) - DYYL(ym, z));
    const float dDyz_y = sy * (DYZL(yp, z) - DYZL(ym, z));
    const float dDyz_z = sz * (DYZL(jc, zp) - DYZL(jc, zm));
    const float dDzz_z = sz * (DZZL(zp) - DZZL(zm));

    const float t1 = dDxx_x + dDxy_y + dDxz_z;
    const float t2 = dDxy_x + dDyy_y + dDyz_z;
    const float t3 = dDxz_x + dDyz_y + dDzz_z;

    const float Dxx0 = DXXL(1, z), Dyy0 = DYYL(jc, z), Dzz0 = DZZL(z);
    const float Dxy0 = DXYL(1, jc, z), Dyz0 = DYZL(jc, z), Dxz0 = DXZL(1, z);

    const float diff = t1 * Cx_c + t2 * Cy_c + t3 * Cz_c
                     + Dxx0 * sXX + Dyy0 * sYY + Dzz0 * sZZ
                     + Dxy0 * cXY + Dyz0 * cYZ + Dxz0 * cXZ;

    // ---- advection (upwind) ----
    const float Vx0 = VXL(1, z), Vy0 = VYL(jc, z), Vz0 = VZL(z);
    const float dVx = sx * (VXL(xp, z) - VXL(xm, z));
    const float dVy = sy * (VYL(yp, z) - VYL(ym, z));
    const float dVz = sz * (VZL(zp) - VZL(zm));

    const float C_x = (Vx0 > 0.f) ? Cx_b : Cx_f;
    const float C_y = (Vy0 > 0.f) ? Cy_b : Cy_f;
    const float C_z = (Vz0 > 0.f) ? Cz_b : Cz_f;

    const float adv = -(Vx0 * C_x + Vy0 * C_y + Vz0 * C_z)
                    - c0 * (dVx + dVy + dVz);

    out[idx] = diff + adv;
}

extern "C" void kernel_launch(void* const* d_in, const int* in_sizes, int n_in,
                              void* d_out, int out_size, void* d_ws, size_t ws_size,
                              hipStream_t stream) {
    const float* C   = (const float*)d_in[0];
    const float* Vx  = (const float*)d_in[1];
    const float* Vy  = (const float*)d_in[2];
    const float* Vz  = (const float*)d_in[3];
    const float* Dxx = (const float*)d_in[4];
    const float* Dxy = (const float*)d_in[5];
    const float* Dxz = (const float*)d_in[6];
    const float* Dyy = (const float*)d_in[7];
    const float* Dyz = (const float*)d_in[8];
    const float* Dzz = (const float*)d_in[9];
    float* out = (float*)d_out;

    // 12800 blocks = 160 x * 40 ytiles * 2 b; block = 640 thr (10 waves).
    dim3 grid(12800, 1, 1);
    dim3 block(160, 4, 1);
    hipLaunchKernelGGL(piano_energy_kernel, grid, block, 0, stream,
                       C, Vx, Vy, Vz, Dxx, Dxy, Dxz, Dyy, Dyz, Dzz, out);
}

// Round 3
// 374.463 us; speedup vs baseline: 1.9140x; 1.3861x over previous
//
#include <hip/hip_runtime.h>

#define N   160
#define SX  (N * N)
#define SY  N

// Round-9: round-6 structure (1 thread = small z-chunk, scalar named locals,
// clamped-offset boundaries, NO LDS, NO aggregates) with 2 z-voxels/thread
// via float2 loads. Halves VMEM instruction count (46 -> 23/voxel) and
// doubles per-thread ILP while keeping the proven low-register dataflow.
// Round-7 lesson: arrays/structs spill (WRITE 491 MB). Round-8 lesson: LDS
// bulk-synchronous staging is slower than flat loads (330 us vs 165).

__device__ __forceinline__ float crossG(const float* __restrict__ P, int gi,
                                        int op1, int of1, int ob1a, int ob1b,
                                        int op2, int of2, int ob2a, int ob2b)
{
    return (P[gi + ob1a + op1] - P[gi + ob1a + of1])
         - (P[gi + ob1b + op1] - P[gi + ob1b + of1])
         + (P[gi + ob2a + op2] - P[gi + ob2a + of2])
         - (P[gi + ob2b + op2] - P[gi + ob2b + of2]);
}

__global__ __launch_bounds__(320, 4) void piano_energy_kernel(
    const float* __restrict__ C,   const float* __restrict__ Vx,
    const float* __restrict__ Vy,  const float* __restrict__ Vz,
    const float* __restrict__ Dxx, const float* __restrict__ Dxy,
    const float* __restrict__ Dxz, const float* __restrict__ Dyy,
    const float* __restrict__ Dyz, const float* __restrict__ Dzz,
    float* __restrict__ out)
{
    const int z0 = threadIdx.x << 1;                 // even z; voxels z0, z0+1
    const int y  = blockIdx.x * 4 + threadIdx.y;
    const int x  = blockIdx.y;                       // block-uniform
    const int b  = blockIdx.z;

    const int idx0 = ((b * N + x) * N + y) * N + z0;

    const bool xlo = (x > 0), xhi = (x < N - 1);
    const bool ylo = (y > 0), yhi = (y < N - 1);
    const bool zloA = (z0 > 0);                      // voxel A: zhi always true
    const bool zhiB = (z0 + 1 < N - 1);              // voxel B: zlo always true

    const int oxp = xhi ?  SX : 0, oxm = xlo ? -SX : 0;
    const int oyp = yhi ?  SY : 0, oym = ylo ? -SY : 0;
    const int ozmA = zloA ? -1 : 0;                  // A's z-1 (clamped)
    const int ozpB = zhiB ?  2 : 1;                  // B's z+1 (clamped), rel idx0

    const float sx  = (xlo && xhi) ? 0.5f : 1.f;
    const float sy  = (ylo && yhi) ? 0.5f : 1.f;
    const float szA = zloA ? 0.5f : 1.f;
    const float szB = zhiB ? 0.5f : 1.f;

#define F2(P, off) (*reinterpret_cast<const float2*>((P) + idx0 + (off)))

    // ---- C neighborhood: 7 float2 + 6 scalars ----
    const float2 cc  = F2(C, 0);
    const float2 cxp = F2(C, oxp), cxm = F2(C, oxm);
    const float2 cyp = F2(C, oyp), cym = F2(C, oym);
    const float2 cab = F2(C, oxm + oyp);             // (x-1, y+1)
    const float2 cba = F2(C, oxp + oym);             // (x+1, y-1)
    const float czmA    = C[idx0 + ozmA];            // A's z-1 (-> cA if clamped)
    const float czpB    = C[idx0 + ozpB];            // B's z+1 (-> cB if clamped)
    const float cxp_zm  = C[idx0 + oxp + ozmA];
    const float cxm_zp2 = C[idx0 + oxm + ozpB];
    const float cyp_zm  = C[idx0 + oyp + ozmA];
    const float cym_zp2 = C[idx0 + oym + ozpB];
    float2 cx2 = make_float2(0.f, 0.f), cy2 = make_float2(0.f, 0.f);
    if (!xlo && xhi) cx2 = F2(C, 2 * SX);            // x==0 plane (uniform)
    if (!ylo && yhi) cy2 = F2(C, 2 * SY);            // y==0 rows

    const float cA = cc.x, cB = cc.y;

    // ---- first derivatives of C ----
    const float CxcA = sx * (cxp.x - cxm.x), CxcB = sx * (cxp.y - cxm.y);
    const float CycA = sy * (cyp.x - cym.x), CycB = sy * (cyp.y - cym.y);
    const float CzcA = szA * (cB - czmA),    CzcB = szB * (czpB - cA);

    const float CxfA = xhi ? (cxp.x - cA) : (cA - cxm.x);
    const float CxfB = xhi ? (cxp.y - cB) : (cB - cxm.y);
    const float CyfA = yhi ? (cyp.x - cA) : (cA - cym.x);
    const float CyfB = yhi ? (cyp.y - cB) : (cB - cym.y);
    const float CzfA = cB - cA;                              // zhiA always
    const float CzfB = zhiB ? (czpB - cB) : (cB - cA);

    const float CxbA = xlo ? (cA - cxm.x) : (cxp.x - cA);
    const float CxbB = xlo ? (cB - cxm.y) : (cxp.y - cB);
    const float CybA = ylo ? (cA - cym.x) : (cyp.x - cA);
    const float CybB = ylo ? (cB - cym.y) : (cyp.y - cB);
    const float CzbA = zloA ? (cA - czmA) : (cB - cA);
    const float CzbB = cB - cA;                              // zloB always

    // ---- pure second derivatives ----
    float sXXA, sXXB, sYYA, sYYB, sZZA, sZZB;
    if (!xhi)      { sXXA = 0.f;                          sXXB = 0.f; }
    else if (xlo)  { sXXA = cxp.x - 2.f * cA + cxm.x;     sXXB = cxp.y - 2.f * cB + cxm.y; }
    else           { sXXA = cx2.x - 2.f * cxp.x + cA;     sXXB = cx2.y - 2.f * cxp.y + cB; }
    if (!yhi)      { sYYA = 0.f;                          sYYB = 0.f; }
    else if (ylo)  { sYYA = cyp.x - 2.f * cA + cym.x;     sYYB = cyp.y - 2.f * cB + cym.y; }
    else           { sYYA = cy2.x - 2.f * cyp.x + cA;     sYYB = cy2.y - 2.f * cyp.y + cB; }
    sZZA = zloA ? (cB - 2.f * cA + czmA) : (czpB - 2.f * cB + cA);   // z==0: C[z+2]-2*C[z+1]+C[z]
    sZZB = zhiB ? (czpB - 2.f * cB + cA) : 0.f;

    // ---- cross second-derivative sums ----
    const int ofx0 = xhi ? 0 : -SX;
    const int ofy0 = yhi ? 0 : -SY;
    const int obx1 = xlo ? 0 : SX, obx0 = obx1 - SX;
    const int oby1 = ylo ? 0 : SY, oby0 = oby1 - SY;

    float cXYA, cXYB;
    if (xlo && xhi && ylo && yhi) {
        cXYA = cxp.x + cxm.x + cyp.x + cym.x - 2.f * cA - cab.x - cba.x;
        cXYB = cxp.y + cxm.y + cyp.y + cym.y - 2.f * cB - cab.y - cba.y;
    } else {
        cXYA = crossG(C, idx0,     oyp, ofy0, obx1, obx0, oxp, ofx0, oby1, oby0);
        cXYB = crossG(C, idx0 + 1, oyp, ofy0, obx1, obx0, oxp, ofx0, oby1, oby0);
    }

    float cXZA, cXZB;
    if (xlo && xhi && zloA) {
        cXZA = cxp.x + cxm.x + cB + czmA - 2.f * cA - cxp_zm - cxm.y;
    } else {
        const int obz1 = zloA ? 0 : 1, obz0 = obz1 - 1;  // A: ozp=1, ofz0=0
        cXZA = crossG(C, idx0, oxp, ofx0, obz1, obz0, 1, 0, obx1, obx0);
    }
    if (xlo && xhi && zhiB) {
        cXZB = cxp.y + cxm.y + czpB + cA - 2.f * cB - cxp.x - cxm_zp2;
    } else {
        const int ozp = zhiB ? 1 : 0, ofz0 = zhiB ? 0 : -1;  // B: obz1=0, obz0=-1
        cXZB = crossG(C, idx0 + 1, oxp, ofx0, 0, -1, ozp, ofz0, obx1, obx0);
    }

    float cYZA, cYZB;
    if (ylo && yhi && zloA) {
        cYZA = cyp.x + cym.x + cB + czmA - 2.f * cA - cyp_zm - cym.y;
    } else {
        const int obz1 = zloA ? 0 : 1, obz0 = obz1 - 1;
        cYZA = crossG(C, idx0, oyp, ofy0, obz1, obz0, 1, 0, oby1, oby0);
    }
    if (ylo && yhi && zhiB) {
        cYZB = cyp.y + cym.y + czpB + cA - 2.f * cB - cyp.x - cym_zp2;
    } else {
        const int ozp = zhiB ? 1 : 0, ofz0 = zhiB ? 0 : -1;
        cYZB = crossG(C, idx0 + 1, oyp, ofy0, 0, -1, ozp, ofz0, oby1, oby0);
    }

    // ---- diffusion: per-D-array phases (each array's values die in-phase) ----
    float t1A, t2A, t3A, accA, t1B, t2B, t3B, accB;
    {
        const float2 dc = F2(Dxx, 0), dp = F2(Dxx, oxp), dm = F2(Dxx, oxm);
        t1A = sx * (dp.x - dm.x);  accA = dc.x * sXXA;
        t1B = sx * (dp.y - dm.y);  accB = dc.y * sXXB;
    }
    {
        const float2 dc = F2(Dxy, 0), dxp2 = F2(Dxy, oxp), dxm2 = F2(Dxy, oxm);
        const float2 dyp2 = F2(Dxy, oyp), dym2 = F2(Dxy, oym);
        t1A += sy * (dyp2.x - dym2.x);  t2A = sx * (dxp2.x - dxm2.x);  accA += dc.x * cXYA;
        t1B += sy * (dyp2.y - dym2.y);  t2B = sx * (dxp2.y - dxm2.y);  accB += dc.y * cXYB;
    }
    {
        const float2 dc = F2(Dxz, 0), dp = F2(Dxz, oxp), dm = F2(Dxz, oxm);
        const float dzm = Dxz[idx0 + ozmA], dzp = Dxz[idx0 + ozpB];
        t1A += szA * (dc.y - dzm);  t3A = sx * (dp.x - dm.x);  accA += dc.x * cXZA;
        t1B += szB * (dzp - dc.x);  t3B = sx * (dp.y - dm.y);  accB += dc.y * cXZB;
    }
    {
        const float2 dc = F2(Dyy, 0), dp = F2(Dyy, oyp), dm = F2(Dyy, oym);
        t2A += sy * (dp.x - dm.x);  accA += dc.x * sYYA;
        t2B += sy * (dp.y - dm.y);  accB += dc.y * sYYB;
    }
    {
        const float2 dc = F2(Dyz, 0), dp = F2(Dyz, oyp), dm = F2(Dyz, oym);
        const float dzm = Dyz[idx0 + ozmA], dzp = Dyz[idx0 + ozpB];
        t2A += szA * (dc.y - dzm);  t3A += sy * (dp.x - dm.x);  accA += dc.x * cYZA;
        t2B += szB * (dzp - dc.x);  t3B += sy * (dp.y - dm.y);  accB += dc.y * cYZB;
    }
    {
        const float2 dc = F2(Dzz, 0);
        const float dzm = Dzz[idx0 + ozmA], dzp = Dzz[idx0 + ozpB];
        t3A += szA * (dc.y - dzm);  accA += dc.x * sZZA;
        t3B += szB * (dzp - dc.x);  accB += dc.y * sZZB;
    }
    accA += t1A * CxcA + t2A * CycA + t3A * CzcA;
    accB += t1B * CxcB + t2B * CycB + t3B * CzcB;

    // ---- advection (upwind), folded per axis ----
    {
        const float2 vc = F2(Vx, 0), vp = F2(Vx, oxp), vm = F2(Vx, oxm);
        accA -= vc.x * ((vc.x > 0.f) ? CxbA : CxfA) + cA * (sx * (vp.x - vm.x));
        accB -= vc.y * ((vc.y > 0.f) ? CxbB : CxfB) + cB * (sx * (vp.y - vm.y));
    }
    {
        const float2 vc = F2(Vy, 0), vp = F2(Vy, oyp), vm = F2(Vy, oym);
        accA -= vc.x * ((vc.x > 0.f) ? CybA : CyfA) + cA * (sy * (vp.x - vm.x));
        accB -= vc.y * ((vc.y > 0.f) ? CybB : CyfB) + cB * (sy * (vp.y - vm.y));
    }
    {
        const float2 vc = F2(Vz, 0);
        const float vzm = Vz[idx0 + ozmA], vzp = Vz[idx0 + ozpB];
        accA -= vc.x * ((vc.x > 0.f) ? CzbA : CzfA) + cA * (szA * (vc.y - vzm));
        accB -= vc.y * ((vc.y > 0.f) ? CzbB : CzfB) + cB * (szB * (vzp - vc.x));
    }

    *reinterpret_cast<float2*>(out + idx0) = make_float2(accA, accB);
#undef F2
}

extern "C" void kernel_launch(void* const* d_in, const int* in_sizes, int n_in,
                              void* d_out, int out_size, void* d_ws, size_t ws_size,
                              hipStream_t stream) {
    const float* C   = (const float*)d_in[0];
    const float* Vx  = (const float*)d_in[1];
    const float* Vy  = (const float*)d_in[2];
    const float* Vz  = (const float*)d_in[3];
    const float* Dxx = (const float*)d_in[4];
    const float* Dxy = (const float*)d_in[5];
    const float* Dxz = (const float*)d_in[6];
    const float* Dyy = (const float*)d_in[7];
    const float* Dyz = (const float*)d_in[8];
    const float* Dzz = (const float*)d_in[9];
    float* out = (float*)d_out;

    // grid.x = y-tiles (40 = 0 mod 8): x+-1 planes are 40 dispatch ids apart
    // -> same XCD under round-robin (the round-6 proven L2-locality layout).
    dim3 grid(N / 4, N, 2);
    dim3 block(N / 2, 4, 1);     // 320 threads, 2 z-voxels per thread
    hipLaunchKernelGGL(piano_energy_kernel, grid, block, 0, stream,
                       C, Vx, Vy, Vz, Dxx, Dxy, Dxz, Dyy, Dyz, Dzz, out);
}